// Round 8
// baseline (110.078 us; speedup 1.0000x reference)
//
#include <hip/hip_runtime.h>

#define HH 64
#define WW 64
#define CC 128
#define FF 256
#define NTAP 9
#define KD 1152   // NTAP*CC
#define XELEMS (8 * HH * WW * CC)         // 4194304
#define XCVT_BLOCKS (XELEMS / (256 * 8))  // 2048
#define WT_BLOCKS 144                     // 36864 threads, 8 k each

typedef __attribute__((ext_vector_type(8))) short bf16x8;
typedef __attribute__((ext_vector_type(4))) float floatx4;

__device__ inline unsigned short f2bf(float v) {
  union { float f; unsigned u; } c; c.f = v;
  unsigned r = (c.u + 0x7FFFu + ((c.u >> 16) & 1u)) >> 16;  // RNE
  return (unsigned short)r;
}
__device__ inline float bflo(unsigned u) {
  union { unsigned u; float f; } c; c.u = u << 16; return c.f;
}
__device__ inline float bfhi(unsigned u) {
  union { unsigned u; float f; } c; c.u = u & 0xFFFF0000u; return c.f;
}
// HW RNE pack: bf16(lo) | bf16(hi)<<16 — same rounding as f2bf for finite inputs.
__device__ inline unsigned cvt_pk_bf16(float lo, float hi) {
  unsigned r;
  asm("v_cvt_pk_bf16_f32 %0, %1, %2" : "=v"(r) : "v"(lo), "v"(hi));
  return r;
}

// Weight-form bilinear (verified rounds 6-7): out = w00*v00 + w10*v10 + w01*v01 + w11*v11
__device__ inline unsigned lerp_word(unsigned u00, unsigned u10, unsigned u01, unsigned u11,
                                     float w00, float w10, float w01, float w11) {
  float rlo = bflo(u00) * w00 + bflo(u10) * w10 + bflo(u01) * w01 + bflo(u11) * w11;
  float rhi = bfhi(u00) * w00 + bfhi(u10) * w10 + bfhi(u01) * w01 + bfhi(u11) * w11;
  return cvt_pk_bf16(rlo, rhi);
}

// Tap offsets packed 2 bits each (meshgrid-faithful order):
// c_iy = {0,0,1,2,2,1,0,2,1} -> 0x18690 ; c_ix = {0,1,1,2,0,2,1,0,2} -> 0x21894
#define IY_PACK 0x18690
#define IX_PACK 0x21894

struct ITap { int b00, b10, b01, b11; float fy, fx; };

__device__ inline ITap tap_from(float2 o2, int yy, int xx, int n) {
  float cy = (float)(yy - 1 + ((IY_PACK >> (2 * n)) & 3)) + o2.x;
  float cx = (float)(xx - 1 + ((IX_PACK >> (2 * n)) & 3)) + o2.y;
  cy = fminf(fmaxf(cy, 0.f), 63.f);
  cx = fminf(fmaxf(cx, 0.f), 63.f);
  const float fy0 = floorf(cy), fx0 = floorf(cx);
  const int y0 = (int)fy0, y1 = (int)ceilf(cy);
  const int x0 = (int)fx0, x1 = (int)ceilf(cx);
  ITap t;
  t.b00 = (y0 * WW + x0) * CC;
  t.b10 = (y1 * WW + x0) * CC;
  t.b01 = (y0 * WW + x1) * CC;
  t.b11 = (y1 * WW + x1) * CC;
  t.fy = cy - fy0;
  t.fx = cx - fx0;
  return t;
}

// ---- Prep: X fp32->bf16; W -> Wtf in MFMA-FRAGMENT order (verified round 7):
// addr(f,kc) = ((kt*2+ks)*16 + fg*4 + ft)*512 + aq*128 + arow*8   (shorts)
__global__ void prep_kernel(const float* __restrict__ X, const float* __restrict__ W,
                            unsigned short* __restrict__ Xb, unsigned short* __restrict__ Wtf) {
  const int blk = blockIdx.x;
  if (blk < XCVT_BLOCKS) {                  // X convert, 8 elems/thread
    const int t = blk * 256 + threadIdx.x;
    const float4* src = (const float4*)(X + (size_t)t * 8);
    float4 a = src[0], b2 = src[1];
    bf16x8 o;
    o[0] = (short)f2bf(a.x);  o[1] = (short)f2bf(a.y);
    o[2] = (short)f2bf(a.z);  o[3] = (short)f2bf(a.w);
    o[4] = (short)f2bf(b2.x); o[5] = (short)f2bf(b2.y);
    o[6] = (short)f2bf(b2.z); o[7] = (short)f2bf(b2.w);
    *(bf16x8*)(Xb + (size_t)t * 8) = o;
  } else {                                  // W repack: thread = (f, one 8-k chunk)
    const int t = (blk - XCVT_BLOCKS) * 256 + threadIdx.x;  // 0..36863
    const int f  = t & 255;
    const int kc = t >> 8;                  // 0..143
    unsigned short o[8];
#pragma unroll
    for (int j = 0; j < 8; ++j)
      o[j] = f2bf(W[(size_t)(kc * 8 + j) * FF + f]);
    const int kt = kc >> 3, ks = (kc >> 2) & 1, aq = kc & 3;
    const int fg = f >> 6, ft = (f >> 4) & 3, arow = f & 15;
    const size_t addr = (size_t)((kt * 2 + ks) * 16 + fg * 4 + ft) * 512 + aq * 128 + arow * 8;
    *(uint4*)(Wtf + addr) = *(uint4*)o;
  }
}

// ---- Fused interp+GEMM: block = one image row = 64 M x 256 F, K = 1152, BK = 64.
// 256 threads = 4 waves; WAVE = 64M x 64F (acc[4][4]) -> B L2 traffic amortized 2x
// vs round 7 (B is M-invariant; traffic scales with 1/M-per-wave). B fragments load
// straight from L2-resident fragment-ordered Wtf (no smB). LDS = smA[2] (16 KB).
// Pipeline (round-7 verified): gathers for tile kt+2 issued at kt, lerped at kt+1;
// one barrier/kt protecting only the 8 KB smA write. Grid 512 -> 2 blocks/CU;
// launch_bounds(256,2) lifts VGPR cap to 256 (no spill; round-5 lesson).
__global__ __launch_bounds__(256, 2) void fused_kernel(
    const unsigned short* __restrict__ Xb, const float* __restrict__ Off,
    const unsigned short* __restrict__ Wtf, const float* __restrict__ bias,
    float* __restrict__ Out)
{
  __shared__ unsigned short smA[2][64 * 64];   // 2 x 8 KB, XOR-swizzled 16B chunks

  const int blk = blockIdx.x;        // 0..511
  const int b   = blk & 7;           // batch == XCD -> Xb slice (1 MB) + Wtf L2-resident
  const int y   = blk >> 3;          // image row; positions x = 0..63
  const int m0  = b * 4096 + y * 64;
  const int tid = threadIdx.x;
  const int wave = tid >> 6, lane = tid & 63;   // wave = F-quarter fg
  const int arow = lane & 15, aq = lane >> 4;
  const int p   = tid >> 2;          // interp: position 0..63
  const int c0  = tid & 3;           // interp: chunks c0 and c0+4

  const unsigned short* xb    = Xb + (size_t)b * (HH * WW * CC);
  const float* offp           = Off + ((size_t)(b * HH + y) * WW + p) * (2 * NTAP);
  const unsigned short* wbase = Wtf + (size_t)wave * 2048 + (size_t)lane * 8;

  floatx4 acc[4][4];
#pragma unroll
  for (int mt = 0; mt < 4; ++mt)
#pragma unroll
    for (int ft = 0; ft < 4; ++ft)
      acc[mt][ft] = (floatx4){0.f, 0.f, 0.f, 0.f};

  const int sa0 = p * 64 + ((c0 ^ (p & 7)) << 3);        // chunk c0
  const int sa1 = p * 64 + (((c0 + 4) ^ (p & 7)) << 3);  // chunk c0+4

  // ---- prologue: tap 0; lerp tile 0 -> smA[0]; gather tile 1 into regs
  ITap tL = tap_from(*(const float2*)offp, y, p, 0);
  uint4 g[2][4];
  {
    const float gy = 1.f - tL.fy, gx = 1.f - tL.fx;
    const float w00 = gy * gx, w10 = tL.fy * gx, w01 = gy * tL.fx, w11 = tL.fy * tL.fx;
#pragma unroll
    for (int cc = 0; cc < 2; ++cc) {
      const int ch = (c0 + cc * 4) * 8;   // tile 0 = tap 0, half 0
      uint4 q00 = *(const uint4*)(xb + tL.b00 + ch);
      uint4 q10 = *(const uint4*)(xb + tL.b10 + ch);
      uint4 q01 = *(const uint4*)(xb + tL.b01 + ch);
      uint4 q11 = *(const uint4*)(xb + tL.b11 + ch);
      uint4 o;
      o.x = lerp_word(q00.x, q10.x, q01.x, q11.x, w00, w10, w01, w11);
      o.y = lerp_word(q00.y, q10.y, q01.y, q11.y, w00, w10, w01, w11);
      o.z = lerp_word(q00.z, q10.z, q01.z, q11.z, w00, w10, w01, w11);
      o.w = lerp_word(q00.w, q10.w, q01.w, q11.w, w00, w10, w01, w11);
      *(uint4*)&smA[0][cc ? sa1 : sa0] = o;
    }
#pragma unroll
    for (int cc = 0; cc < 2; ++cc) {
      const int ch1 = (8 + c0 + cc * 4) * 8;  // tile 1 = tap 0, half 1
      g[cc][0] = *(const uint4*)(xb + tL.b00 + ch1);
      g[cc][1] = *(const uint4*)(xb + tL.b10 + ch1);
      g[cc][2] = *(const uint4*)(xb + tL.b01 + ch1);
      g[cc][3] = *(const uint4*)(xb + tL.b11 + ch1);
    }
  }
  ITap tG = tL;
  __syncthreads();

  int cur = 0;
  for (int kt = 0; kt < 18; ++kt) {
    const unsigned short* wk = wbase + (size_t)kt * 16384;  // (kt*2)*16*512 shorts

    // ---- B ks=0 fragment loads (L2, coalesced: base + lane*16B)
    bf16x8 b0[4], b1[4];
#pragma unroll
    for (int ft = 0; ft < 4; ++ft)
      b0[ft] = *(const bf16x8*)(wk + ft * 512);

    // ---- A fragments from smA[cur] (8 x ds_read_b128, conflict-free)
    bf16x8 afr[2][4];
#pragma unroll
    for (int ks = 0; ks < 2; ++ks) {
      const int slot = (((ks * 4 + aq) ^ (arow & 7)) << 3);
#pragma unroll
      for (int mt = 0; mt < 4; ++mt)
        afr[ks][mt] = *(const bf16x8*)&smA[cur][(mt * 16 + arow) * 64 + slot];
    }

    // ---- B ks=1 fragment loads
#pragma unroll
    for (int ft = 0; ft < 4; ++ft)
      b1[ft] = *(const bf16x8*)(wk + 8192 + ft * 512);

    // ---- issue gathers for tile kt+2 (consumed next iteration, cross-barrier)
    uint4 gn[2][4];
    if (kt <= 15) {
      if ((kt & 1) == 0)
        tG = tap_from(*(const float2*)(offp + 2 * ((kt + 2) >> 1)), y, p, (kt + 2) >> 1);
#pragma unroll
      for (int cc = 0; cc < 2; ++cc) {
        const int ch = ((kt & 1) * 8 + c0 + cc * 4) * 8;  // half of tile kt+2 = kt&1
        gn[cc][0] = *(const uint4*)(xb + tG.b00 + ch);
        gn[cc][1] = *(const uint4*)(xb + tG.b10 + ch);
        gn[cc][2] = *(const uint4*)(xb + tG.b01 + ch);
        gn[cc][3] = *(const uint4*)(xb + tG.b11 + ch);
      }
    }

    // ---- lerp last iteration's gathers -> tile kt+1 into smA[cur^1]
    // (VALU phase: covers the b0/b1/gather load latency issued above)
    if (kt <= 16) {
      const float gy = 1.f - tL.fy, gx = 1.f - tL.fx;
      const float w00 = gy * gx, w10 = tL.fy * gx, w01 = gy * tL.fx, w11 = tL.fy * tL.fx;
#pragma unroll
      for (int cc = 0; cc < 2; ++cc) {
        uint4 o;
        o.x = lerp_word(g[cc][0].x, g[cc][1].x, g[cc][2].x, g[cc][3].x, w00, w10, w01, w11);
        o.y = lerp_word(g[cc][0].y, g[cc][1].y, g[cc][2].y, g[cc][3].y, w00, w10, w01, w11);
        o.z = lerp_word(g[cc][0].z, g[cc][1].z, g[cc][2].z, g[cc][3].z, w00, w10, w01, w11);
        o.w = lerp_word(g[cc][0].w, g[cc][1].w, g[cc][2].w, g[cc][3].w, w00, w10, w01, w11);
        *(uint4*)&smA[cur ^ 1][cc ? sa1 : sa0] = o;
      }
    }

    // ---- MFMA: 32 per wave per kt (2 ks x 4 mt x 4 ft)
#pragma unroll
    for (int mt = 0; mt < 4; ++mt)
#pragma unroll
      for (int ft = 0; ft < 4; ++ft)
        acc[mt][ft] = __builtin_amdgcn_mfma_f32_16x16x32_bf16(
            afr[0][mt], b0[ft], acc[mt][ft], 0, 0, 0);
#pragma unroll
    for (int mt = 0; mt < 4; ++mt)
#pragma unroll
      for (int ft = 0; ft < 4; ++ft)
        acc[mt][ft] = __builtin_amdgcn_mfma_f32_16x16x32_bf16(
            afr[1][mt], b1[ft], acc[mt][ft], 0, 0, 0);

    // ---- roll the gather pipeline
    if (kt <= 15) {
#pragma unroll
      for (int cc = 0; cc < 2; ++cc)
#pragma unroll
        for (int q2 = 0; q2 < 4; ++q2)
          g[cc][q2] = gn[cc][q2];
    }
    __syncthreads();   // drains lgkm (smA writes)
    cur ^= 1;
    tL = tG;
  }

  // ---- epilogue: plain stores (verified clean-write pattern)
  float bv[4];
#pragma unroll
  for (int ft = 0; ft < 4; ++ft)
    bv[ft] = bias[wave * 64 + ft * 16 + arow];
#pragma unroll
  for (int mt = 0; mt < 4; ++mt) {
#pragma unroll
    for (int ft = 0; ft < 4; ++ft) {
      const int f = wave * 64 + ft * 16 + arow;
#pragma unroll
      for (int r = 0; r < 4; ++r) {
        const int m = m0 + mt * 16 + aq * 4 + r;
        Out[(size_t)m * FF + f] = acc[mt][ft][r] + bv[ft];
      }
    }
  }
}

extern "C" void kernel_launch(void* const* d_in, const int* in_sizes, int n_in,
                              void* d_out, int out_size, void* d_ws, size_t ws_size,
                              hipStream_t stream) {
  const float* X    = (const float*)d_in[0];
  const float* Off  = (const float*)d_in[1];
  const float* W    = (const float*)d_in[2];
  const float* bias = (const float*)d_in[3];
  float* Out = (float*)d_out;

  unsigned short* Wtf = (unsigned short*)d_ws;                 // 294912 shorts
  unsigned short* Xb  = Wtf + (size_t)FF * KD;                 // 4194304 shorts

  prep_kernel<<<XCVT_BLOCKS + WT_BLOCKS, 256, 0, stream>>>(X, W, Xb, Wtf);
  fused_kernel<<<512, 256, 0, stream>>>(Xb, Off, Wtf, bias, Out);
}